// Round 6
// baseline (493.076 us; speedup 1.0000x reference)
//
#include <hip/hip_runtime.h>

// SoftMorphology soft-skeleton: columns-in-registers, shuffle-based stencil.
// Round-6: same verified algorithm as rounds 4/5; resource fixes:
//   * amdgpu_waves_per_eu(2,2): allocator budgets 256 VGPR/wave -> the
//     ~165-reg demand fits with NO spills (round 5: capped at 128, spilled;
//     WRITE_SIZE showed +146 MB/dispatch of scratch stores).
//   * 256-thread blocks = 4 independent waves, each its own y-strip: 4x
//     fewer workgroups, wg-slot occupancy cap removed. No LDS, no barriers.
//   * Two launches (STAGES=6 then 5), RV=8: R = RV+2*(STAGES+1) = 22 / 20
//     rows/lane -> f[22]=88 VGPR + sk[8]=32 + temps ~= 165 < 256.
//
// Layout: wave owns 256 cols (4/lane, float4), R rows in registers.
// Vertical neighbors register-local; horizontal = 2 shuffles/row.
// grid.x=5 waves tile W=1024 with disjoint quad-aligned write windows
// (208x4, 192); left halo 8 >= STAGES+1 = 7. Region-edge clamped reads
// contaminate <= 1 col/stage inward; halo keeps it dead.
//
// Per stage one in-place ascending pass: at iteration i,
//   e = erode(old f[i-1..i+1]) -> f[i-1] (window shifts up 1/stage);
//   h0 = hmax3(e) rolling (h2,h1,h0 = new rows i-3,i-2,i-1);
//   skel row j=i-2 (new-idx): dilate = vmax3(h2,h1,h0); A_{t-1} = pm1.
//
// Borders: staged loads clamp row/col (replicate guards). EROSION absorbs
// replicate guards (center term dominates the min; induction per stage).
// DILATE needs exact extension: per-lane overrides at image cols 0/1023,
// h-row swap at image rows 0/1023.

#define W 1024
#define H 1024
#define NBATCH 16
#define RV 8

__device__ __forceinline__ float min3f(float a, float b, float c) {
  return fminf(fminf(a, b), c);
}
__device__ __forceinline__ float max3f(float a, float b, float c) {
  return fmaxf(fmaxf(a, b), c);
}

template <int STAGES, bool FIRST, bool EOUT>
__global__ __attribute__((amdgpu_waves_per_eu(2, 2)))
__launch_bounds__(256) void skel_pass(
    const float* __restrict__ in,   // E_s  (img when FIRST)
    float* __restrict__ e_out,      // E_{s+STAGES} out (EOUT only)
    float* __restrict__ skel) {
  constexpr int HALO = STAGES + 1;
  constexpr int R = RV + 2 * HALO;

  const int l = threadIdx.x & 63;           // lane
  const int wid = threadIdx.x >> 6;         // wave 0..3 -> y sub-strip
  const int w = blockIdx.x;                 // 0..4 column windows
  const int y0 = (blockIdx.y * 4 + wid) * RV;
  const size_t base = (size_t)blockIdx.z * (size_t)(W * H);

  const int rx = 208 * w - 8 + 4 * l;       // lane's col start (may be OOB)
  const int cq = min(max(rx, 0), W - 4);    // clamped load col
  const bool mL = (rx == 0);                // lane's c0 is image col 0
  const bool mR = (rx == W - 4);            // lane's c3 is image col 1023
  const bool top = (y0 == 0);
  const bool bot = (y0 + RV == H);
  const int wend = min(208 * (w + 1), W);
  const bool wr = (rx >= 208 * w) && (rx < wend);

  // ---- stage input rows (row/col clamped) ----
  float4 f[R];
#pragma unroll
  for (int i = 0; i < R; ++i) {
    const int gy = min(max(y0 - HALO + i, 0), H - 1);
    f[i] = *(const float4*)(in + base + (size_t)gy * W + cq);
  }

  float4 sk[RV];
  if (!FIRST) {
#pragma unroll
    for (int k = 0; k < RV; ++k)
      sk[k] = *(const float4*)(skel + base + (size_t)(y0 + k) * W + cq);
  }

#pragma unroll
  for (int t = 1; t <= STAGES; ++t) {
    const int V = R - 2 * (t - 1);          // valid rows at stage entry
    float4 pm1 = f[0];
    float4 h0, h1, h2;
#pragma unroll
    for (int i = 1; i <= V - 2; ++i) {
      const float4 cur = f[i];
      const float4 nxt = f[i + 1];
      // erode: vertical min3 then cross with horizontal neighbors
      float4 e;
      const float vmx = min3f(pm1.x, cur.x, nxt.x);
      const float vmy = min3f(pm1.y, cur.y, nxt.y);
      const float vmz = min3f(pm1.z, cur.z, nxt.z);
      const float vmw = min3f(pm1.w, cur.w, nxt.w);
      float Lin = __shfl_up(cur.w, 1, 64);
      if (mL) Lin = cur.x;                  // image col 0: ext == center
      float Rin = __shfl_down(cur.x, 1, 64);
      if (mR) Rin = cur.w;                  // image col 1023
      e.x = min3f(vmx, Lin, cur.y);
      e.y = min3f(vmy, cur.x, cur.z);
      e.z = min3f(vmz, cur.y, cur.w);
      e.w = min3f(vmw, cur.z, Rin);
      f[i - 1] = e;                         // in-place, window shifts up

      // h = hmax3(e) for new-row m=i-1, needed for m in [jlo-1, jhi+1]
      if (i >= HALO - t && i <= HALO - t + RV + 1) {
        float Lh = __shfl_up(e.w, 1, 64);
        if (mL) Lh = e.x;
        float Rh = __shfl_down(e.x, 1, 64);
        if (mR) Rh = e.w;
        h0.x = max3f(Lh, e.x, e.y);
        h0.y = max3f(e.x, e.y, e.z);
        h0.z = max3f(e.y, e.z, e.w);
        h0.w = max3f(e.z, e.w, Rh);
      }
      // update for skel row k: new-idx center j=i-2; pm1 == A_{t-1} there
      if (i >= HALO - t + 2 && i <= HALO - t + RV + 1) {
        const int k = i - 2 - (HALO - t);
        float4 ha = h2, hb = h0;
        if (k == 0 && top) ha = h1;         // image row 0: ext == center
        if (k == RV - 1 && bot) hb = h1;    // image row 1023
        float4 dd, dl;
        dd.x = max3f(ha.x, h1.x, hb.x);
        dd.y = max3f(ha.y, h1.y, hb.y);
        dd.z = max3f(ha.z, h1.z, hb.z);
        dd.w = max3f(ha.w, h1.w, hb.w);
        dl.x = fmaxf(pm1.x - dd.x, 0.f);
        dl.y = fmaxf(pm1.y - dd.y, 0.f);
        dl.z = fmaxf(pm1.z - dd.z, 0.f);
        dl.w = fmaxf(pm1.w - dd.w, 0.f);
        if (FIRST && t == 1) {
          sk[k] = dl;
        } else {
          sk[k].x += fmaxf(dl.x - sk[k].x * dl.x, 0.f);
          sk[k].y += fmaxf(dl.y - sk[k].y * dl.y, 0.f);
          sk[k].z += fmaxf(dl.z - sk[k].z * dl.z, 0.f);
          sk[k].w += fmaxf(dl.w - sk[k].w * dl.w, 0.f);
        }
      }
      h2 = h1;
      h1 = h0;
      pm1 = cur;
    }
  }

  // ---- stores: write lanes only (disjoint quad-aligned windows) ----
  if (wr) {
#pragma unroll
    for (int k = 0; k < RV; ++k)
      *(float4*)(skel + base + (size_t)(y0 + k) * W + rx) = sk[k];
    if (EOUT) {
      // after STAGES stages, row y0+k sits at f[HALO - STAGES + k] = f[1+k]
#pragma unroll
      for (int k = 0; k < RV; ++k)
        *(float4*)(e_out + base + (size_t)(y0 + k) * W + rx) = f[1 + k];
    }
  }
}

extern "C" void kernel_launch(void* const* d_in, const int* in_sizes, int n_in,
                              void* d_out, int out_size, void* d_ws,
                              size_t ws_size, hipStream_t stream) {
  const float* img = (const float*)d_in[0];
  float* skel = (float*)d_out;
  float* E = (float*)d_ws;  // 64 MiB: E6 between the two launches

  dim3 grid(5, H / (4 * RV), NBATCH);  // 5 x 32 x 16 = 2560 blocks
  // L1: k=0 init + iters 1..5; reads img, writes E6 + skel.
  skel_pass<6, true, true><<<grid, 256, 0, stream>>>(img, E, skel);
  // L2: iters 6..10; reads E6 + skel, writes skel.
  skel_pass<5, false, false><<<grid, 256, 0, stream>>>(E, nullptr, skel);
}

// Round 7
// 479.229 us; speedup vs baseline: 1.0289x; 1.0289x over previous
//
#include <hip/hip_runtime.h>

// SoftMorphology soft-skeleton: columns-in-registers, shuffle-based stencil.
// Round-7: same verified algorithm as rounds 4-6. Root cause of rounds 4-6
// slowness: the inner erode loop bound V = R-2*(t-1) is only constant after
// the OUTER loop unrolls, so clang never fully unrolled it -> f[i] was
// runtime-indexed -> f[] lived in SCRATCH (rule #20). Evidence: WRITE_SIZE
// excess scaled with R (R=30: +1.2GB, R=18: +146MB, R=22: +492MB) while
// VGPR_Count stayed 128.
// Fix: per-stage template<int T> function -> V is constexpr inside each
// instantiation; #pragma unroll on constant-trip loops; if constexpr chain.
//
// Layout: 256-thread blocks = 4 independent waves, each owning its own
// RV=8-row y-strip (no LDS, no barriers). Wave owns 256 cols (4/lane,
// float4), R rows in registers. Vertical neighbors register-local;
// horizontal = 2 shuffles/row. grid.x=5 column windows of 208/192 write
// cols, left halo 8 >= STAGES+1=7; region-edge clamped reads contaminate
// <=1 col/stage inward, halo keeps it dead.
//
// Two launches: STAGES=6 (init + iters 1..5, writes E6+skel) and STAGES=5
// (iters 6..10, writes skel). R = RV+2*(STAGES+1) = 22 / 20 rows/lane:
// f[22]=88 VGPR + sk[8]=32 + temps ~= 165 < 256 (launch_bounds min 2
// waves/EU -> 256-VGPR budget).
//
// Borders: staged loads clamp row/col (replicate guards). EROSION absorbs
// replicate guards (center term dominates the min; induction per stage).
// DILATE needs exact extension: per-lane overrides at image cols 0/1023,
// h-row swap at image rows 0/1023.

#define W 1024
#define H 1024
#define NBATCH 16
#define RV 8

__device__ __forceinline__ float min3f(float a, float b, float c) {
  return fminf(fminf(a, b), c);
}
__device__ __forceinline__ float max3f(float a, float b, float c) {
  return fmaxf(fmaxf(a, b), c);
}

// One erosion stage T (1-based) of a launch with STAGES stages total.
// In-place ascending pass; window shifts up one row index per stage.
template <int T, int STAGES, bool FIRST, int R>
__device__ __forceinline__ void do_stage(float4 (&f)[R], float4 (&sk)[RV],
                                         const bool mL, const bool mR,
                                         const bool top, const bool bot) {
  constexpr int HALO = STAGES + 1;
  constexpr int V = R - 2 * (T - 1);  // valid rows at stage entry
  float4 pm1 = f[0];
  float4 h0 = {0, 0, 0, 0}, h1 = {0, 0, 0, 0}, h2 = {0, 0, 0, 0};
#pragma unroll
  for (int i = 1; i <= V - 2; ++i) {
    const float4 cur = f[i];
    const float4 nxt = f[i + 1];
    // erode: vertical min3 then cross with horizontal neighbors
    float4 e;
    const float vmx = min3f(pm1.x, cur.x, nxt.x);
    const float vmy = min3f(pm1.y, cur.y, nxt.y);
    const float vmz = min3f(pm1.z, cur.z, nxt.z);
    const float vmw = min3f(pm1.w, cur.w, nxt.w);
    float Lin = __shfl_up(cur.w, 1, 64);
    if (mL) Lin = cur.x;                  // image col 0: ext == center
    float Rin = __shfl_down(cur.x, 1, 64);
    if (mR) Rin = cur.w;                  // image col 1023
    e.x = min3f(vmx, Lin, cur.y);
    e.y = min3f(vmy, cur.x, cur.z);
    e.z = min3f(vmz, cur.y, cur.w);
    e.w = min3f(vmw, cur.z, Rin);
    f[i - 1] = e;                         // in-place, window shifts up

    // h = hmax3(e) for new-row m=i-1, needed for m in [jlo-1, jhi+1]
    if (i >= HALO - T && i <= HALO - T + RV + 1) {
      float Lh = __shfl_up(e.w, 1, 64);
      if (mL) Lh = e.x;
      float Rh = __shfl_down(e.x, 1, 64);
      if (mR) Rh = e.w;
      h0.x = max3f(Lh, e.x, e.y);
      h0.y = max3f(e.x, e.y, e.z);
      h0.z = max3f(e.y, e.z, e.w);
      h0.w = max3f(e.z, e.w, Rh);
    }
    // update for skel row k: new-idx center j=i-2; pm1 == A_{t-1} there
    if (i >= HALO - T + 2 && i <= HALO - T + RV + 1) {
      const int k = i - 2 - (HALO - T);
      float4 ha = h2, hb = h0;
      if (k == 0 && top) ha = h1;         // image row 0: ext == center
      if (k == RV - 1 && bot) hb = h1;    // image row 1023
      float4 dd, dl;
      dd.x = max3f(ha.x, h1.x, hb.x);
      dd.y = max3f(ha.y, h1.y, hb.y);
      dd.z = max3f(ha.z, h1.z, hb.z);
      dd.w = max3f(ha.w, h1.w, hb.w);
      dl.x = fmaxf(pm1.x - dd.x, 0.f);
      dl.y = fmaxf(pm1.y - dd.y, 0.f);
      dl.z = fmaxf(pm1.z - dd.z, 0.f);
      dl.w = fmaxf(pm1.w - dd.w, 0.f);
      if (FIRST && T == 1) {
        sk[k] = dl;
      } else {
        sk[k].x += fmaxf(dl.x - sk[k].x * dl.x, 0.f);
        sk[k].y += fmaxf(dl.y - sk[k].y * dl.y, 0.f);
        sk[k].z += fmaxf(dl.z - sk[k].z * dl.z, 0.f);
        sk[k].w += fmaxf(dl.w - sk[k].w * dl.w, 0.f);
      }
    }
    h2 = h1;
    h1 = h0;
    pm1 = cur;
  }
}

template <int STAGES, bool FIRST, bool EOUT>
__global__ __launch_bounds__(256, 2) void skel_pass(
    const float* __restrict__ in,   // E_s  (img when FIRST)
    float* __restrict__ e_out,      // E_{s+STAGES} out (EOUT only)
    float* __restrict__ skel) {
  constexpr int HALO = STAGES + 1;
  constexpr int R = RV + 2 * HALO;

  const int l = threadIdx.x & 63;           // lane
  const int wid = threadIdx.x >> 6;         // wave 0..3 -> y sub-strip
  const int w = blockIdx.x;                 // 0..4 column windows
  const int y0 = (blockIdx.y * 4 + wid) * RV;
  const size_t base = (size_t)blockIdx.z * (size_t)(W * H);

  const int rx = 208 * w - 8 + 4 * l;       // lane's col start (may be OOB)
  const int cq = min(max(rx, 0), W - 4);    // clamped load col
  const bool mL = (rx == 0);                // lane's c0 is image col 0
  const bool mR = (rx == W - 4);            // lane's c3 is image col 1023
  const bool top = (y0 == 0);
  const bool bot = (y0 + RV == H);
  const int wend = min(208 * (w + 1), W);
  const bool wr = (rx >= 208 * w) && (rx < wend);

  // ---- stage input rows (row/col clamped) ----
  float4 f[R];
#pragma unroll
  for (int i = 0; i < R; ++i) {
    const int gy = min(max(y0 - HALO + i, 0), H - 1);
    f[i] = *(const float4*)(in + base + (size_t)gy * W + cq);
  }

  float4 sk[RV];
  if (!FIRST) {
#pragma unroll
    for (int k = 0; k < RV; ++k)
      sk[k] = *(const float4*)(skel + base + (size_t)(y0 + k) * W + cq);
  }

  // ---- stages, each with constexpr trip counts (keeps f[] in VGPRs) ----
  do_stage<1, STAGES, FIRST>(f, sk, mL, mR, top, bot);
  do_stage<2, STAGES, FIRST>(f, sk, mL, mR, top, bot);
  do_stage<3, STAGES, FIRST>(f, sk, mL, mR, top, bot);
  do_stage<4, STAGES, FIRST>(f, sk, mL, mR, top, bot);
  if constexpr (STAGES >= 5) do_stage<5, STAGES, FIRST>(f, sk, mL, mR, top, bot);
  if constexpr (STAGES >= 6) do_stage<6, STAGES, FIRST>(f, sk, mL, mR, top, bot);

  // ---- stores: write lanes only (disjoint quad-aligned windows) ----
  if (wr) {
#pragma unroll
    for (int k = 0; k < RV; ++k)
      *(float4*)(skel + base + (size_t)(y0 + k) * W + rx) = sk[k];
    if (EOUT) {
      // after STAGES stages, row y0+k sits at f[HALO - STAGES + k] = f[1+k]
#pragma unroll
      for (int k = 0; k < RV; ++k)
        *(float4*)(e_out + base + (size_t)(y0 + k) * W + rx) = f[1 + k];
    }
  }
}

extern "C" void kernel_launch(void* const* d_in, const int* in_sizes, int n_in,
                              void* d_out, int out_size, void* d_ws,
                              size_t ws_size, hipStream_t stream) {
  const float* img = (const float*)d_in[0];
  float* skel = (float*)d_out;
  float* E = (float*)d_ws;  // 64 MiB: E6 between the two launches

  dim3 grid(5, H / (4 * RV), NBATCH);  // 5 x 32 x 16 = 2560 blocks
  // L1: k=0 init + iters 1..5; reads img, writes E6 + skel.
  skel_pass<6, true, true><<<grid, 256, 0, stream>>>(img, E, skel);
  // L2: iters 6..10; reads E6 + skel, writes skel.
  skel_pass<5, false, false><<<grid, 256, 0, stream>>>(E, nullptr, skel);
}